// Round 4
// baseline (326.109 us; speedup 1.0000x reference)
//
#include <hip/hip_runtime.h>

#define D_MODEL 1024
#define TSEQ    4096
#define BATCH   4
#define MROWS   (BATCH * TSEQ)   // 16384
#define KDIM    1024
#define NDIM    1024
#define EPSV    1e-6f

typedef __attribute__((ext_vector_type(8))) short short8;
typedef __attribute__((ext_vector_type(4))) float floatx4;

__device__ inline unsigned short f2bf(float f) {
  unsigned u = __float_as_uint(f);
  unsigned r = (u + 0x7FFFu + ((u >> 16) & 1u)) >> 16;  // RNE
  return (unsigned short)r;
}
__device__ inline float bf2f(unsigned short h) {
  return __uint_as_float(((unsigned)h) << 16);
}
__device__ inline float phi_f(float x) { return x > 0.f ? x + 1.f : __expf(x); }

// ---------------- fused prep: fp32->bf16 (x + 4 weights) + zero ksum/kvsum ----
#define NX4 4194304   // x float4 count
#define NW4 262144    // one weight float4 count
#define NZ4 2048      // ksum+kvsum float4 count

__global__ __launch_bounds__(256) void prep_kernel(
    const float* __restrict__ x,  const float* __restrict__ wq,
    const float* __restrict__ wk, const float* __restrict__ wv,
    const float* __restrict__ wg,
    unsigned short* __restrict__ xb,  unsigned short* __restrict__ wqb,
    unsigned short* __restrict__ wkb, unsigned short* __restrict__ wvb,
    unsigned short* __restrict__ wgb, float* __restrict__ zbase)
{
  long i = (long)blockIdx.x * 256 + threadIdx.x;
  const float* src; unsigned short* dst; long j = i;
  if (j < NX4) { src = x; dst = xb; }
  else {
    j -= NX4;
    if (j < NW4) { src = wq; dst = wqb; }
    else { j -= NW4;
      if (j < NW4) { src = wk; dst = wkb; }
      else { j -= NW4;
        if (j < NW4) { src = wv; dst = wvb; }
        else { j -= NW4;
          if (j < NW4) { src = wg; dst = wgb; }
          else { j -= NW4;
            if (j < NZ4) { float4 zz = {0.f,0.f,0.f,0.f}; ((float4*)zbase)[j] = zz; }
            return;
          }
        }
      }
    }
  }
  float4 f = ((const float4*)src)[j];
  ushort4 o;
  o.x = f2bf(f.x); o.y = f2bf(f.y); o.z = f2bf(f.z); o.w = f2bf(f.w);
  ((ushort4*)dst)[j] = o;
}

#define BM 128
#define BN 128
#define BK 64    // 16 K-iters; LDS slot swizzle keeps banks even

// Swizzled LDS tile: slot s (16B chunks) holds global (row = s>>3,
// colgroup = (s&7) ^ (row&7)). Reader: slot(row, g) = row*8 + (g ^ (row&7)).
// Bank group for b128 read = 4*(g ^ (row&7)) -> 8 lanes per 4-bank group,
// perfectly even across the wave.

// ---------------- phase 1: k/v GEMM with in-register fused reduction --------
__global__ __launch_bounds__(256) void gemm_kv_kernel(
    const unsigned short* __restrict__ A,
    const unsigned short* __restrict__ Wk, const unsigned short* __restrict__ Wv,
    float* __restrict__ ksum, float* __restrict__ kvsum)
{
  const int bn = blockIdx.x;   // 0..7
  const int bm = blockIdx.y;   // 0..127

  __shared__ __align__(16) unsigned short As[BM * BK];
  __shared__ __align__(16) unsigned short Bk[BN * BK];
  __shared__ __align__(16) unsigned short Bv[BN * BK];

  const int tid  = threadIdx.x;
  const int lane = tid & 63;
  const int w    = tid >> 6;          // 0..3
  const int wr   = (w >> 1) * 64;
  const int wc   = (w & 1) * 64;

  floatx4 ak[4][4], av[4][4];
#pragma unroll
  for (int i = 0; i < 4; i++)
#pragma unroll
    for (int j = 0; j < 4; j++) {
      floatx4 zz = {0.f,0.f,0.f,0.f}; ak[i][j] = zz; av[i][j] = zz;
    }

  const unsigned short* Ablk  = A  + (size_t)bm * BM * KDIM;
  const unsigned short* Bkblk = Wk + (size_t)bn * BN * KDIM;
  const unsigned short* Bvblk = Wv + (size_t)bn * BN * KDIM;

  const int la  = lane & 15;
  const int lg  = lane >> 4;          // 0..3: k-group within 32-k step
  const int lx  = lane & 7;           // swizzle xor term (row&7 == la&7)

  for (int kt = 0; kt < KDIM; kt += BK) {
    __syncthreads();
#pragma unroll
    for (int c = 0; c < 4; c++) {
      int s   = tid + c * 256;        // slot 0..1023
      int r   = s >> 3;
      int gc  = (s & 7) ^ (r & 7);
      size_t goff = (size_t)r * KDIM + kt + gc * 8;
      __builtin_amdgcn_global_load_lds(
          (const __attribute__((address_space(1))) void*)(Ablk + goff),
          (__attribute__((address_space(3))) void*)(As + (size_t)s * 8), 16, 0, 0);
      __builtin_amdgcn_global_load_lds(
          (const __attribute__((address_space(1))) void*)(Bkblk + goff),
          (__attribute__((address_space(3))) void*)(Bk + (size_t)s * 8), 16, 0, 0);
      __builtin_amdgcn_global_load_lds(
          (const __attribute__((address_space(1))) void*)(Bvblk + goff),
          (__attribute__((address_space(3))) void*)(Bv + (size_t)s * 8), 16, 0, 0);
    }
    __syncthreads();

#pragma unroll
    for (int ks = 0; ks < 2; ks++) {
      const int gx = ((ks * 4 + lg) ^ lx);   // swizzled slot column
      short8 af[4], bk[4], bv[4];
#pragma unroll
      for (int i = 0; i < 4; i++) {
        af[i] = *(const short8*)&As[((wr + i * 16 + la) * 8 + gx) * 8];
        bk[i] = *(const short8*)&Bk[((wc + i * 16 + la) * 8 + gx) * 8];
        bv[i] = *(const short8*)&Bv[((wc + i * 16 + la) * 8 + gx) * 8];
      }
#pragma unroll
      for (int i = 0; i < 4; i++)
#pragma unroll
        for (int j = 0; j < 4; j++) {
          ak[i][j] = __builtin_amdgcn_mfma_f32_16x16x32_bf16(af[i], bk[j], ak[i][j], 0, 0, 0);
          av[i][j] = __builtin_amdgcn_mfma_f32_16x16x32_bf16(af[i], bv[j], av[i][j], 0, 0, 0);
        }
    }
  }

  // ---- fused column reduction ----
  const int b = bm >> 5;
  float kp[4] = {0.f,0.f,0.f,0.f};
  float vp[4] = {0.f,0.f,0.f,0.f};
#pragma unroll
  for (int j = 0; j < 4; j++)
#pragma unroll
    for (int i = 0; i < 4; i++)
#pragma unroll
      for (int r = 0; r < 4; r++) {
        float kk = phi_f(ak[i][j][r]);
        kp[j] += kk;
        vp[j] += kk * av[i][j][r];
      }
#pragma unroll
  for (int j = 0; j < 4; j++) {
    kp[j] += __shfl_xor(kp[j], 16, 64); kp[j] += __shfl_xor(kp[j], 32, 64);
    vp[j] += __shfl_xor(vp[j], 16, 64); vp[j] += __shfl_xor(vp[j], 32, 64);
  }
  if (lane < 16) {
#pragma unroll
    for (int j = 0; j < 4; j++) {
      int col = bn * BN + wc + j * 16 + lane;
      atomicAdd(ksum  + (size_t)b * D_MODEL + col, kp[j]);
      atomicAdd(kvsum + (size_t)b * D_MODEL + col, vp[j]);
    }
  }
}

// ---------------- phase 2: q/g GEMM with fused finalize ---------------------
__global__ __launch_bounds__(512) void gemm_qg_kernel(
    const unsigned short* __restrict__ A,
    const unsigned short* __restrict__ Wq, const unsigned short* __restrict__ Wg,
    const float* __restrict__ x, const float* __restrict__ bg,
    const float* __restrict__ ksum, const float* __restrict__ kvsum,
    float* __restrict__ out)
{
  const int bn = blockIdx.x;   // 0..7
  const int bm = blockIdx.y;   // 0..127

  __shared__ __align__(16) unsigned short As[BM * BK];
  __shared__ __align__(16) unsigned short Bq[BN * BK];
  __shared__ __align__(16) unsigned short Bg[BN * BK];
  __shared__ float o_lds[2 * BM];

  const int tid  = threadIdx.x;
  const int lane = tid & 63;
  const int w    = tid >> 6;          // 0..7
  const int is_g = w >> 2;
  const int wl   = w & 3;
  const int wr   = (wl >> 1) * 64;
  const int wc   = (wl & 1) * 64;

  floatx4 acc[4][4];
#pragma unroll
  for (int i = 0; i < 4; i++)
#pragma unroll
    for (int j = 0; j < 4; j++) { floatx4 zz = {0.f,0.f,0.f,0.f}; acc[i][j] = zz; }

  const unsigned short* Ablk  = A + (size_t)bm * BM * KDIM;
  const unsigned short* Bqblk = Wq + (size_t)bn * BN * KDIM;
  const unsigned short* Bgblk = Wg + (size_t)bn * BN * KDIM;

  const int la = lane & 15;
  const int lg = lane >> 4;
  const int lx = lane & 7;
  const unsigned short* Bsm = is_g ? Bg : Bq;

  for (int kt = 0; kt < KDIM; kt += BK) {
    __syncthreads();
#pragma unroll
    for (int c = 0; c < 2; c++) {
      int s   = tid + c * 512;        // slot 0..1023
      int r   = s >> 3;
      int gc  = (s & 7) ^ (r & 7);
      size_t goff = (size_t)r * KDIM + kt + gc * 8;
      __builtin_amdgcn_global_load_lds(
          (const __attribute__((address_space(1))) void*)(Ablk + goff),
          (__attribute__((address_space(3))) void*)(As + (size_t)s * 8), 16, 0, 0);
      __builtin_amdgcn_global_load_lds(
          (const __attribute__((address_space(1))) void*)(Bqblk + goff),
          (__attribute__((address_space(3))) void*)(Bq + (size_t)s * 8), 16, 0, 0);
      __builtin_amdgcn_global_load_lds(
          (const __attribute__((address_space(1))) void*)(Bgblk + goff),
          (__attribute__((address_space(3))) void*)(Bg + (size_t)s * 8), 16, 0, 0);
    }
    __syncthreads();

#pragma unroll
    for (int ks = 0; ks < 2; ks++) {
      const int gx = ((ks * 4 + lg) ^ lx);
      short8 af[4], bfg[4];
#pragma unroll
      for (int i = 0; i < 4; i++) {
        af[i]  = *(const short8*)&As[((wr + i * 16 + la) * 8 + gx) * 8];
        bfg[i] = *(const short8*)&Bsm[((wc + i * 16 + la) * 8 + gx) * 8];
      }
#pragma unroll
      for (int i = 0; i < 4; i++)
#pragma unroll
        for (int j = 0; j < 4; j++)
          acc[i][j] = __builtin_amdgcn_mfma_f32_16x16x32_bf16(af[i], bfg[j], acc[i][j], 0, 0, 0);
    }
  }

  // ---- fused finalize ----
  const int b  = bm >> 5;
  const int ro = (lane >> 4) * 4;
  const int co = lane & 15;
  const int hl = wc >> 6;

  if (!is_g) {
    float kvv[4], ksv[4];
#pragma unroll
    for (int j = 0; j < 4; j++) {
      int col = bn * BN + wc + j * 16 + co;
      kvv[j] = kvsum[(size_t)b * D_MODEL + col];
      ksv[j] = ksum [(size_t)b * D_MODEL + col];
    }
#pragma unroll
    for (int i = 0; i < 4; i++)
#pragma unroll
      for (int r = 0; r < 4; r++) {
        float s = 0.f, z = 0.f;
#pragma unroll
        for (int j = 0; j < 4; j++) {
          float qq = phi_f(acc[i][j][r]);
          s += qq * kvv[j]; z += qq * ksv[j];
        }
#pragma unroll
        for (int m = 1; m < 16; m <<= 1) {
          s += __shfl_xor(s, m, 64);
          z += __shfl_xor(z, m, 64);
        }
        if (co == 0) o_lds[hl * BM + wr + i * 16 + ro + r] = s / (z + EPSV);
      }
  }
  __syncthreads();
  if (is_g) {
    float bgv[4];
#pragma unroll
    for (int j = 0; j < 4; j++) bgv[j] = bg[bn * BN + wc + j * 16 + co];
#pragma unroll
    for (int i = 0; i < 4; i++)
#pragma unroll
      for (int r = 0; r < 4; r++) {
        int rowl = wr + i * 16 + ro + r;
        int grow = bm * BM + rowl;
        float ov = o_lds[hl * BM + rowl];
#pragma unroll
        for (int j = 0; j < 4; j++) {
          int gcol = bn * BN + wc + j * 16 + co;
          float gt = 1.f / (1.f + __expf(-(acc[i][j][r] + bgv[j])));
          float xv = x[(size_t)grow * D_MODEL + gcol];
          out[(size_t)grow * D_MODEL + gcol] = gt * ov + (1.f - gt) * xv;
        }
      }
  }
}

extern "C" void kernel_launch(void* const* d_in, const int* in_sizes, int n_in,
                              void* d_out, int out_size, void* d_ws, size_t ws_size,
                              hipStream_t stream) {
  (void)in_sizes; (void)n_in; (void)out_size; (void)ws_size;
  const float* x  = (const float*)d_in[0];
  const float* Wq = (const float*)d_in[1];
  const float* Wk = (const float*)d_in[2];
  const float* Wv = (const float*)d_in[3];
  /* d_in[4] = Wo — unused by the reference */
  const float* Wg = (const float*)d_in[5];
  const float* bg = (const float*)d_in[6];
  float* out = (float*)d_out;

  char* ws = (char*)d_ws;
  const size_t xel = (size_t)MROWS * D_MODEL;
  const size_t wel = (size_t)NDIM * KDIM;
  unsigned short* xbf = (unsigned short*)ws; ws += xel * 2;
  unsigned short* wqb = (unsigned short*)ws; ws += wel * 2;
  unsigned short* wkb = (unsigned short*)ws; ws += wel * 2;
  unsigned short* wvb = (unsigned short*)ws; ws += wel * 2;
  unsigned short* wgb = (unsigned short*)ws; ws += wel * 2;
  float* ksum  = (float*)ws; ws += (size_t)BATCH * D_MODEL * 4;  // contiguous
  float* kvsum = (float*)ws; ws += (size_t)BATCH * D_MODEL * 4;

  // 1) fused converts + zero
  const long total4 = (long)NX4 + 4L * NW4 + NZ4;
  prep_kernel<<<(int)((total4 + 255) / 256), 256, 0, stream>>>(
      x, Wq, Wk, Wv, Wg, xbf, wqb, wkb, wvb, wgb, ksum);

  // 2) phase 1: k/v with fused reduction
  dim3 g1(NDIM / BN, MROWS / BM);
  gemm_kv_kernel<<<g1, 256, 0, stream>>>(xbf, wkb, wvb, ksum, kvsum);

  // 3) phase 2: q/g with fused finalize
  dim3 g2(NDIM / BN, MROWS / BM);
  gemm_qg_kernel<<<g2, 512, 0, stream>>>(xbf, wqb, wgb, x, bg, ksum, kvsum, out);
}